// Round 3
// baseline (154.669 us; speedup 1.0000x reference)
//
#include <hip/hip_runtime.h>

// DependencyGenerator: out[b][i][j] = 1.0, then scatter dep_emb[dep_type] at
// (dep_i, dep_j) per batch row; last duplicate index wins (numpy semantics).
// b=128, L=512.

#define SEQ_L   512
#define LM1     511               // scatter entries per row
#define ROWELEM (SEQ_L * SEQ_L)   // 262144 floats per row
#define BPR     16                // blocks per row
#define CHUNK   (ROWELEM / BPR)   // 16384 floats per block
#define NT      256               // threads per block

// Native vector type: __builtin_nontemporal_store rejects HIP_vector_type.
typedef float vfloat4 __attribute__((ext_vector_type(4)));

__global__ __launch_bounds__(NT) void depmask_kernel(
    const int*   __restrict__ dep_i,
    const int*   __restrict__ dep_j,
    const int*   __restrict__ dep_type,
    const float* __restrict__ dep_emb,
    float*       __restrict__ out)
{
    __shared__ int   s_idx[LM1];
    __shared__ float s_val[LM1];

    const int row   = blockIdx.x / BPR;
    const int chunk = blockIdx.x % BPR;
    const int t     = threadIdx.x;

    // 1) Fill this block's chunk with 1.0 FIRST (stores fire-and-forget;
    //    staging loads below overlap the drain). Nontemporal: write-once
    //    streaming data, don't keep dirty lines resident in L2.
    float* rowout = out + (size_t)row * ROWELEM + (size_t)chunk * CHUNK;
    vfloat4* o4 = reinterpret_cast<vfloat4*>(rowout);
    const vfloat4 ones = {1.f, 1.f, 1.f, 1.f};
    #pragma unroll
    for (int v = 0; v < CHUNK / 4 / NT; ++v) {
        __builtin_nontemporal_store(ones, &o4[(size_t)v * NT + t]);
    }

    // 2) Stage this row's scatter entries (indices + gathered emb values).
    const int base = row * LM1;
    for (int k = t; k < LM1; k += NT) {
        const int i  = dep_i[base + k];
        const int j  = dep_j[base + k];
        const int ty = dep_type[base + k];
        s_idx[k] = i * SEQ_L + j;
        s_val[k] = dep_emb[ty];     // 53-entry table, L1-resident
    }

    // 3) Barrier: drains vmcnt (fill stores complete -> scatter may overwrite)
    //    and lgkmcnt (LDS staging visible to all threads).
    __syncthreads();

    // 4) Scatter entries falling in this chunk; last duplicate index wins.
    const int lo = chunk * CHUNK, hi = lo + CHUNK;
    for (int k = t; k < LM1; k += NT) {
        const int idx = s_idx[k];
        if (idx >= lo && idx < hi) {
            bool last = true;
            for (int k2 = k + 1; k2 < LM1; ++k2) {
                if (s_idx[k2] == idx) { last = false; break; }
            }
            if (last) out[(size_t)row * ROWELEM + idx] = s_val[k];
        }
    }
}

extern "C" void kernel_launch(void* const* d_in, const int* in_sizes, int n_in,
                              void* d_out, int out_size, void* d_ws, size_t ws_size,
                              hipStream_t stream) {
    const int*   dep_i    = (const int*)  d_in[0];
    const int*   dep_j    = (const int*)  d_in[1];
    const int*   dep_type = (const int*)  d_in[2];
    // d_in[3] = seq_len scalar (512) -- compile-time constant here
    const float* dep_emb  = (const float*)d_in[4];
    float*       out      = (float*)      d_out;

    const int b = in_sizes[0] / LM1;   // 128
    depmask_kernel<<<dim3(b * BPR), dim3(NT), 0, stream>>>(
        dep_i, dep_j, dep_type, dep_emb, out);
}

// Round 4
// 154.150 us; speedup vs baseline: 1.0034x; 1.0034x over previous
//
#include <hip/hip_runtime.h>

// DependencyGenerator: out[b][i][j] = 1.0, then scatter dep_emb[dep_type] at
// (dep_i, dep_j) per batch row; last duplicate index wins (numpy semantics).
// b=128, L=512.
// R4: BPR=16 + fill-first (from R3) but REGULAR stores — R3's nontemporal
// hint dropped achieved BW 1.37->0.88 TB/s (evict-first defeats L2 write
// combining for a pure store stream).

#define SEQ_L   512
#define LM1     511               // scatter entries per row
#define ROWELEM (SEQ_L * SEQ_L)   // 262144 floats per row
#define BPR     16                // blocks per row
#define CHUNK   (ROWELEM / BPR)   // 16384 floats per block
#define NT      256               // threads per block

typedef float vfloat4 __attribute__((ext_vector_type(4)));

__global__ __launch_bounds__(NT) void depmask_kernel(
    const int*   __restrict__ dep_i,
    const int*   __restrict__ dep_j,
    const int*   __restrict__ dep_type,
    const float* __restrict__ dep_emb,
    float*       __restrict__ out)
{
    __shared__ int   s_idx[LM1];
    __shared__ float s_val[LM1];

    const int row   = blockIdx.x / BPR;
    const int chunk = blockIdx.x % BPR;
    const int t     = threadIdx.x;

    // 1) Fill this block's chunk with 1.0 first (fire-and-forget stores;
    //    the staging loads below overlap the store drain).
    float* rowout = out + (size_t)row * ROWELEM + (size_t)chunk * CHUNK;
    vfloat4* o4 = reinterpret_cast<vfloat4*>(rowout);
    const vfloat4 ones = {1.f, 1.f, 1.f, 1.f};
    #pragma unroll
    for (int v = 0; v < CHUNK / 4 / NT; ++v) {
        o4[(size_t)v * NT + t] = ones;
    }

    // 2) Stage this row's scatter entries (indices + gathered emb values).
    const int base = row * LM1;
    for (int k = t; k < LM1; k += NT) {
        const int i  = dep_i[base + k];
        const int j  = dep_j[base + k];
        const int ty = dep_type[base + k];
        s_idx[k] = i * SEQ_L + j;
        s_val[k] = dep_emb[ty];     // 53-entry table, L1-resident
    }

    // 3) Barrier: drains vmcnt (fill stores complete -> scatter may overwrite)
    //    and lgkmcnt (LDS staging visible).
    __syncthreads();

    // 4) Scatter entries falling in this chunk; last duplicate index wins.
    const int lo = chunk * CHUNK, hi = lo + CHUNK;
    for (int k = t; k < LM1; k += NT) {
        const int idx = s_idx[k];
        if (idx >= lo && idx < hi) {
            bool last = true;
            for (int k2 = k + 1; k2 < LM1; ++k2) {
                if (s_idx[k2] == idx) { last = false; break; }
            }
            if (last) out[(size_t)row * ROWELEM + idx] = s_val[k];
        }
    }
}

extern "C" void kernel_launch(void* const* d_in, const int* in_sizes, int n_in,
                              void* d_out, int out_size, void* d_ws, size_t ws_size,
                              hipStream_t stream) {
    const int*   dep_i    = (const int*)  d_in[0];
    const int*   dep_j    = (const int*)  d_in[1];
    const int*   dep_type = (const int*)  d_in[2];
    // d_in[3] = seq_len scalar (512) -- compile-time constant here
    const float* dep_emb  = (const float*)d_in[4];
    float*       out      = (float*)      d_out;

    const int b = in_sizes[0] / LM1;   // 128
    depmask_kernel<<<dim3(b * BPR), dim3(NT), 0, stream>>>(
        dep_i, dep_j, dep_type, dep_emb, out);
}

// Round 5
// 94.102 us; speedup vs baseline: 1.6436x; 1.6381x over previous
//
#include <hip/hip_runtime.h>

// DependencyGenerator, R5: two-kernel split.
//   fill_kernel:    pure grid-stride float4 fill of 1.0 (contiguous global
//                   frontier -> DRAM page locality; no LDS/barrier/scan).
//   scatter_kernel: one block per batch row, last-duplicate-wins scatter of
//                   dep_emb[dep_type] at dep_i*L+dep_j.
// Stream order gives fill -> scatter dependency.

#define SEQ_L   512
#define LM1     511               // scatter entries per row
#define ROWELEM (SEQ_L * SEQ_L)   // 262144 floats per row
#define NT      256

typedef float vfloat4 __attribute__((ext_vector_type(4)));

__global__ __launch_bounds__(NT) void fill_kernel(float* __restrict__ out,
                                                  size_t n4)
{
    const vfloat4 ones = {1.f, 1.f, 1.f, 1.f};
    vfloat4* o4 = reinterpret_cast<vfloat4*>(out);
    const size_t stride = (size_t)gridDim.x * NT;
    #pragma unroll 4
    for (size_t i = (size_t)blockIdx.x * NT + threadIdx.x; i < n4; i += stride)
        o4[i] = ones;
}

__global__ __launch_bounds__(NT) void scatter_kernel(
    const int*   __restrict__ dep_i,
    const int*   __restrict__ dep_j,
    const int*   __restrict__ dep_type,
    const float* __restrict__ dep_emb,
    float*       __restrict__ out)
{
    __shared__ int   s_idx[LM1];
    __shared__ float s_val[LM1];

    const int row = blockIdx.x;
    const int t   = threadIdx.x;

    const int base = row * LM1;
    for (int k = t; k < LM1; k += NT) {
        const int i  = dep_i[base + k];
        const int j  = dep_j[base + k];
        const int ty = dep_type[base + k];
        s_idx[k] = i * SEQ_L + j;
        s_val[k] = dep_emb[ty];     // 53-entry table, L1-resident
    }
    __syncthreads();

    // Last duplicate index wins (numpy sequential-scatter semantics).
    for (int k = t; k < LM1; k += NT) {
        const int idx = s_idx[k];
        bool last = true;
        for (int k2 = k + 1; k2 < LM1; ++k2) {
            if (s_idx[k2] == idx) { last = false; break; }
        }
        if (last) out[(size_t)row * ROWELEM + idx] = s_val[k];
    }
}

extern "C" void kernel_launch(void* const* d_in, const int* in_sizes, int n_in,
                              void* d_out, int out_size, void* d_ws, size_t ws_size,
                              hipStream_t stream) {
    const int*   dep_i    = (const int*)  d_in[0];
    const int*   dep_j    = (const int*)  d_in[1];
    const int*   dep_type = (const int*)  d_in[2];
    // d_in[3] = seq_len scalar (512) -- compile-time constant here
    const float* dep_emb  = (const float*)d_in[4];
    float*       out      = (float*)      d_out;

    const int b = in_sizes[0] / LM1;            // 128
    const size_t n4 = (size_t)b * ROWELEM / 4;  // float4 count (8.4M)

    fill_kernel<<<dim3(2048), dim3(NT), 0, stream>>>(out, n4);
    scatter_kernel<<<dim3(b), dim3(NT), 0, stream>>>(
        dep_i, dep_j, dep_type, dep_emb, out);
}

// Round 6
// 91.252 us; speedup vs baseline: 1.6950x; 1.0312x over previous
//
#include <hip/hip_runtime.h>

// DependencyGenerator, R6: two-kernel split, fill grid matched to the
// rocclr fillBufferAligned configuration observed at 6.9 TB/s (86% peak):
// ~1 block/CU, 256 threads, grid-stride 16B stores. Fewer concurrent write
// frontiers -> DRAM page-burst locality. (Measured ladder: 2048 chunked
// blocks 0.9 TB/s, 1024 chunked 1.35, 2048 grid-stride 1.9, rocclr@~256
// grid-stride 6.9.)

#define SEQ_L   512
#define LM1     511               // scatter entries per row
#define ROWELEM (SEQ_L * SEQ_L)   // 262144 floats per row
#define NT      256
#define FILL_BLOCKS 256           // ~1 block per CU

typedef float vfloat4 __attribute__((ext_vector_type(4)));

__global__ __launch_bounds__(NT) void fill_kernel(float* __restrict__ out,
                                                  unsigned int n4)
{
    const vfloat4 ones = {1.f, 1.f, 1.f, 1.f};
    vfloat4* o4 = reinterpret_cast<vfloat4*>(out);
    const unsigned int stride = FILL_BLOCKS * NT;          // 65536 float4 = 1 MB
    unsigned int i = blockIdx.x * NT + threadIdx.x;
    #pragma unroll 4
    for (; i < n4; i += stride)
        o4[i] = ones;
}

__global__ __launch_bounds__(NT) void scatter_kernel(
    const int*   __restrict__ dep_i,
    const int*   __restrict__ dep_j,
    const int*   __restrict__ dep_type,
    const float* __restrict__ dep_emb,
    float*       __restrict__ out)
{
    __shared__ int   s_idx[LM1];
    __shared__ float s_val[LM1];

    const int row = blockIdx.x;
    const int t   = threadIdx.x;

    const int base = row * LM1;
    for (int k = t; k < LM1; k += NT) {
        const int i  = dep_i[base + k];
        const int j  = dep_j[base + k];
        const int ty = dep_type[base + k];
        s_idx[k] = i * SEQ_L + j;
        s_val[k] = dep_emb[ty];     // 53-entry table, L1-resident
    }
    __syncthreads();

    // Last duplicate index wins (numpy sequential-scatter semantics).
    for (int k = t; k < LM1; k += NT) {
        const int idx = s_idx[k];
        bool last = true;
        for (int k2 = k + 1; k2 < LM1; ++k2) {
            if (s_idx[k2] == idx) { last = false; break; }
        }
        if (last) out[(size_t)row * ROWELEM + idx] = s_val[k];
    }
}

extern "C" void kernel_launch(void* const* d_in, const int* in_sizes, int n_in,
                              void* d_out, int out_size, void* d_ws, size_t ws_size,
                              hipStream_t stream) {
    const int*   dep_i    = (const int*)  d_in[0];
    const int*   dep_j    = (const int*)  d_in[1];
    const int*   dep_type = (const int*)  d_in[2];
    // d_in[3] = seq_len scalar (512) -- compile-time constant here
    const float* dep_emb  = (const float*)d_in[4];
    float*       out      = (float*)      d_out;

    const int b = in_sizes[0] / LM1;                        // 128
    const unsigned int n4 = (unsigned int)((size_t)b * ROWELEM / 4);  // 8.4M

    fill_kernel<<<dim3(FILL_BLOCKS), dim3(NT), 0, stream>>>(out, n4);
    scatter_kernel<<<dim3(b), dim3(NT), 0, stream>>>(
        dep_i, dep_j, dep_type, dep_emb, out);
}

// Round 7
// 38.193 us; speedup vs baseline: 4.0497x; 2.3893x over previous
//
#include <hip/hip_runtime.h>

// DependencyGenerator, R7: two-kernel split.
// R6 post-mortem: scatter's duplicate scan had a data-dependent `break`
// -> latency-bound dependent ds_reads (~120cyc x ~765 iters) ~= 60+us.
// R7 removes the break (fixed trip count, OR-reduction) so the compiler
// unrolls and pipelines the LDS reads (throughput ~6cyc). Fill unchanged.

#define SEQ_L   512
#define LM1     511               // scatter entries per row
#define ROWELEM (SEQ_L * SEQ_L)   // 262144 floats per row
#define NT      256
#define FILL_BLOCKS 256           // ~1 block per CU (matches rocclr fill cfg)

typedef float vfloat4 __attribute__((ext_vector_type(4)));

__global__ __launch_bounds__(NT) void fill_kernel(float* __restrict__ out,
                                                  unsigned int n4)
{
    const vfloat4 ones = {1.f, 1.f, 1.f, 1.f};
    vfloat4* o4 = reinterpret_cast<vfloat4*>(out);
    const unsigned int stride = FILL_BLOCKS * NT;          // 65536 float4 = 1 MB
    unsigned int i = blockIdx.x * NT + threadIdx.x;
    #pragma unroll 4
    for (; i < n4; i += stride)
        o4[i] = ones;
}

__global__ __launch_bounds__(NT) void scatter_kernel(
    const int*   __restrict__ dep_i,
    const int*   __restrict__ dep_j,
    const int*   __restrict__ dep_type,
    const float* __restrict__ dep_emb,
    float*       __restrict__ out)
{
    __shared__ int   s_idx[LM1];
    __shared__ float s_val[LM1];

    const int row = blockIdx.x;
    const int t   = threadIdx.x;

    const int base = row * LM1;
    for (int k = t; k < LM1; k += NT) {
        const int i  = dep_i[base + k];
        const int j  = dep_j[base + k];
        const int ty = dep_type[base + k];
        s_idx[k] = i * SEQ_L + j;
        s_val[k] = dep_emb[ty];     // 53-entry table, L1-resident
    }
    __syncthreads();

    // Last duplicate index wins. NO early break: fixed trip count lets the
    // compiler unroll & pipeline the ds_reads (throughput-bound, ~2us).
    for (int k = t; k < LM1; k += NT) {
        const int idx = s_idx[k];
        bool last = true;
        for (int k2 = k + 1; k2 < LM1; ++k2)
            last &= (s_idx[k2] != idx);
        if (last) out[(size_t)row * ROWELEM + idx] = s_val[k];
    }
}

extern "C" void kernel_launch(void* const* d_in, const int* in_sizes, int n_in,
                              void* d_out, int out_size, void* d_ws, size_t ws_size,
                              hipStream_t stream) {
    const int*   dep_i    = (const int*)  d_in[0];
    const int*   dep_j    = (const int*)  d_in[1];
    const int*   dep_type = (const int*)  d_in[2];
    // d_in[3] = seq_len scalar (512) -- compile-time constant here
    const float* dep_emb  = (const float*)d_in[4];
    float*       out      = (float*)      d_out;

    const int b = in_sizes[0] / LM1;                        // 128
    const unsigned int n4 = (unsigned int)((size_t)b * ROWELEM / 4);  // 8.4M

    fill_kernel<<<dim3(FILL_BLOCKS), dim3(NT), 0, stream>>>(out, n4);
    scatter_kernel<<<dim3(b), dim3(NT), 0, stream>>>(
        dep_i, dep_j, dep_type, dep_emb, out);
}